// Round 15
// baseline (164.263 us; speedup 1.0000x reference)
//
#include <hip/hip_runtime.h>
#include <math.h>

namespace {

constexpr int NQ = 10;
constexpr int NL = 4;
constexpr float PI_F = 3.14159265358979323846f;

// One batch element per wave. Packed {re,im} float2 per amp. SU(2)
// exploitation: U = W*RY(a) has u11 = conj(u00), u10 = -conj(u01), so only
// u00,u01 are built; second gate row via conjugated asm variants
// (cmulc/cfmamc); lane-gate coefficient selects are single sign-bit XORs.
// Lane exchanges: DPP for masks 1,2,8; ds_swizzle for 4,16,32. Composed
// 5-CNOT lane perm -> ds_bpermute. Layer-trailing C(9->0) deferred into
// next layer's wire-0 gate; measurement fixes the final pending swap and
// uses permlane-sum (R11-verified) for the 16/32 butterfly stages.
// Layer 0 uses the |0> product-state shortcut.
// R14 post-mortem: launch_bounds(256,8)'s 64-VGPR cap made the SU(2) asm
// chains spill (FETCH 5MB/WRITE 11MB scratch). (256,7) lifts the cap to
// ~72 — natural pressure fits, no spill.

typedef float v2 __attribute__((ext_vector_type(2)));

__device__ __forceinline__ float readlane_f(float v, int lane_const) {
  return __int_as_float(__builtin_amdgcn_readlane(__float_as_int(v), lane_const));
}
__device__ __forceinline__ float bperm_f(int addr4, float v) {
  return __int_as_float(__builtin_amdgcn_ds_bpermute(addr4, __float_as_int(v)));
}

// own + partner(lane^MASK) — direction-agnostic sum (R11-verified); used in
// the measurement butterfly only.
__device__ __forceinline__ float plsum32(float v) {
  float a = v, b = v;
  asm("v_permlane32_swap_b32 %0, %1" : "+v"(a), "+v"(b));
  return a + b;
}
__device__ __forceinline__ float plsum16(float v) {
  float a = v, b = v;
  asm("v_permlane16_swap_b32 %0, %1" : "+v"(a), "+v"(b));
  return a + b;
}

// xor-lane exchange for masks 1,2,8 (DPP) and 4,16,32 (ds_swizzle).
template<int MASK>
__device__ __forceinline__ float lxor(float v) {
  if constexpr (MASK == 1 || MASK == 2 || MASK == 8) {
    constexpr int ctrl = (MASK == 1) ? 0xB1 : (MASK == 2) ? 0x4E : 0x128;
    int i = __float_as_int(v);
    return __int_as_float(__builtin_amdgcn_update_dpp(i, i, ctrl, 0xF, 0xF, true));
  } else {
    return __shfl_xor(v, MASK, 64);
  }
}
template<int MASK>
__device__ __forceinline__ v2 lxor2(v2 v) {
  v2 r; r.x = lxor<MASK>(v.x); r.y = lxor<MASK>(v.y); return r;
}

// ---- packed complex arithmetic ({re,im} in one VGPR pair) ----
// d = u (*) a
__device__ __forceinline__ v2 cmul(v2 u, v2 a) {
  v2 d;
  asm("v_pk_mul_f32 %0, %1, %2 op_sel:[0,0] op_sel_hi:[0,1]\n\t"
      "v_pk_fma_f32 %0, %1, %2, %0 op_sel:[1,1,0] op_sel_hi:[1,0,1] neg_lo:[1,0,0]"
      : "=&v"(d) : "v"(u), "v"(a));
  return d;
}
// d = acc + u (*) a
__device__ __forceinline__ v2 cfma(v2 u, v2 a, v2 acc) {
  v2 d;
  asm("v_pk_fma_f32 %0, %1, %2, %3 op_sel:[0,0,0] op_sel_hi:[0,1,1]\n\t"
      "v_pk_fma_f32 %0, %1, %2, %0 op_sel:[1,1,0] op_sel_hi:[1,0,1] neg_lo:[1,0,0]"
      : "=&v"(d) : "v"(u), "v"(a), "v"(acc));
  return d;
}
// d = conj(u) (*) a : lo = u.lo*a.lo + u.hi*a.hi ; hi = u.lo*a.hi - u.hi*a.lo
__device__ __forceinline__ v2 cmulc(v2 u, v2 a) {
  v2 d;
  asm("v_pk_mul_f32 %0, %1, %2 op_sel:[0,0] op_sel_hi:[0,1]\n\t"
      "v_pk_fma_f32 %0, %1, %2, %0 op_sel:[1,1,0] op_sel_hi:[1,0,1] neg_hi:[1,0,0]"
      : "=&v"(d) : "v"(u), "v"(a));
  return d;
}
// d = acc - conj(u) (*) a
__device__ __forceinline__ v2 cfmamc(v2 u, v2 a, v2 acc) {
  v2 d;
  asm("v_pk_fma_f32 %0, %1, %2, %3 op_sel:[0,0,0] op_sel_hi:[0,1,1] neg_lo:[1,0,0] neg_hi:[1,0,0]\n\t"
      "v_pk_fma_f32 %0, %1, %2, %0 op_sel:[1,1,0] op_sel_hi:[1,0,1] neg_lo:[1,0,0]"
      : "=&v"(d) : "v"(u), "v"(a), "v"(acc));
  return d;
}

// Gate on state bit P with SU(2) matrix given by u00,u01 only.
// sgn = per-lane sign mask ((lane>>bit)&1)<<31 for this gate's lane bit
// (unused for P<4). SW: pending xor-32 lane swap on odd regs consumed here
// (only legal for P==9).
template<int P, bool SW>
__device__ __forceinline__ void apply_u(v2 (&s)[16], v2 u00, v2 u01, int sgn) {
  if constexpr (P < 4) {
    constexpr int bit = 1 << P;
#pragma unroll
    for (int r = 0; r < 16; ++r) {
      if ((r & bit) == 0) {
        int r1 = r | bit;
        v2 a0 = s[r], a1 = s[r1];
        s[r]  = cfma(u01, a1, cmul(u00, a0));            // u00*a0 + u01*a1
        s[r1] = cfmamc(u01, a0, cmulc(u00, a1));         // conj(u00)*a1 - conj(u01)*a0
      }
    }
  } else {
    constexpr int mask = 1 << (P - 4);
    // hi lane: self = u11 = conj(u00) = {u00.x, -u00.y}
    //          partner = u10 = -conj(u01) = {-u01.x, u01.y}
    // lo lane: self = u00, partner = u01.  One XOR each via sgn.
    v2 cA, cB;
    cA.x = u00.x;
    cA.y = __int_as_float(__float_as_int(u00.y) ^ sgn);
    cB.x = __int_as_float(__float_as_int(u01.x) ^ sgn);
    cB.y = u01.y;
#pragma unroll
    for (int r = 0; r < 16; ++r) {
      v2 p = lxor2<mask>(s[r]);
      if constexpr (SW) {
        if (r & 1) { s[r] = cfma(cA, p, cmul(cB, s[r])); continue; }
      }
      s[r] = cfma(cB, p, cmul(cA, s[r]));
    }
  }
}

// CNOT chain: (9,8)(8,7)(7,6)(6,5)(5,4) composed bpermute | (4,3) cndmask |
// (3,2)(2,1)(1,0) reg swaps | (0,9) DEFERRED.
__device__ __forceinline__ void cnot_block(v2 (&s)[16], int lane, int srcl4) {
#pragma unroll
  for (int r = 0; r < 16; ++r) {
    s[r].x = bperm_f(srcl4, s[r].x);
    s[r].y = bperm_f(srcl4, s[r].y);
  }
  bool ctrl = (lane & 1) != 0;
#pragma unroll
  for (int r = 0; r < 8; ++r) {
    int r1 = r | 8;
    v2 t0 = s[r], t1 = s[r1];
    s[r]  = ctrl ? t1 : t0;
    s[r1] = ctrl ? t0 : t1;
  }
#pragma unroll
  for (int r = 8; r < 12; ++r) { v2 t = s[r]; s[r] = s[r | 4]; s[r | 4] = t; }
  {
    const int rs[4] = {4, 5, 12, 13};
#pragma unroll
    for (int k = 0; k < 4; ++k) {
      int r = rs[k];
      v2 t = s[r]; s[r] = s[r | 2]; s[r | 2] = t;
    }
  }
#pragma unroll
  for (int r = 2; r < 16; r += 4) { v2 t = s[r]; s[r] = s[r | 1]; s[r | 1] = t; }
}

// Layer 0 on |0>: product state. Wire w (0..5) -> lane bit (5-w);
// wires 6..9 -> reg bits 3..0. amp = prod of column-0 entries
// (col0 of U = {u00, u10 = -conj(u01)}).
__device__ __forceinline__ void init_product(v2 (&s)[16], const float4* wmat,
                                             float cx, float sx, int lane) {
  v2 u0, u1;
#define C0(i) { float4 wa = wmat[(i)]; \
    v2 wa0 = {wa.x, wa.y}, wa1 = {wa.z, wa.w}; \
    float ca = readlane_f(cx, (i)), sa = readlane_f(sx, (i)); \
    u0 = ca * wa0 + sa * wa1; \
    v2 t01 = ca * wa1 - sa * wa0; \
    u1.x = -t01.x; u1.y = t01.y; }
  v2 f;
  C0(0); f = (lane & 32) ? u1 : u0;
  C0(1); f = cmul((lane & 16) ? u1 : u0, f);
  C0(2); f = cmul((lane & 8) ? u1 : u0, f);
  C0(3); f = cmul((lane & 4) ? u1 : u0, f);
  C0(4); f = cmul((lane & 2) ? u1 : u0, f);
  C0(5); f = cmul((lane & 1) ? u1 : u0, f);
  v2 q6_0, q6_1, q7_0, q7_1, q8_0, q8_1, q9_0, q9_1;
  C0(6); q6_0 = u0; q6_1 = u1;
  C0(7); q7_0 = u0; q7_1 = u1;
  C0(8); q8_0 = u0; q8_1 = u1;
  C0(9); q9_0 = u0; q9_1 = u1;
#undef C0
  v2 qa0 = cmul(q8_0, q9_0), qa1 = cmul(q8_0, q9_1);
  v2 qa2 = cmul(q8_1, q9_0), qa3 = cmul(q8_1, q9_1);
  v2 qb0 = cmul(q6_0, q7_0), qb1 = cmul(q6_0, q7_1);
  v2 qb2 = cmul(q6_1, q7_0), qb3 = cmul(q6_1, q7_1);
  v2 fa0 = cmul(qa0, f), fa1 = cmul(qa1, f), fa2 = cmul(qa2, f), fa3 = cmul(qa3, f);
  s[0]  = cmul(qb0, fa0); s[1]  = cmul(qb0, fa1); s[2]  = cmul(qb0, fa2); s[3]  = cmul(qb0, fa3);
  s[4]  = cmul(qb1, fa0); s[5]  = cmul(qb1, fa1); s[6]  = cmul(qb1, fa2); s[7]  = cmul(qb1, fa3);
  s[8]  = cmul(qb2, fa0); s[9]  = cmul(qb2, fa1); s[10] = cmul(qb2, fa2); s[11] = cmul(qb2, fa3);
  s[12] = cmul(qb3, fa0); s[13] = cmul(qb3, fa1); s[14] = cmul(qb3, fa2); s[15] = cmul(qb3, fa3);
}

template<int L, bool PEND>
__device__ __forceinline__ void layer_gates(v2 (&s)[16], const float4* wmat,
                                            float cxv, float sxv,
                                            const int (&sgn)[6]) {
  // sgn index: lane-bit k (mask 1<<k) -> sgn[k]; gate i has state bit 9-i,
  // lane bit 5-i for i<6.
#define FUSED(i, SW) { \
    float4 wa = wmat[L * NQ + (i)]; \
    float ca = readlane_f(cxv, (i)); \
    float sa = readlane_f(sxv, (i)); \
    v2 wa0 = {wa.x, wa.y}, wa1 = {wa.z, wa.w}; \
    v2 u00 = ca * wa0 + sa * wa1, u01 = ca * wa1 - sa * wa0; \
    apply_u<9 - (i), SW>(s, u00, u01, ((i) < 6) ? sgn[5 - (i)] : 0); }
  FUSED(0, PEND)            // wire0 = bit9 = lane xor 32; consumes pending swap
  FUSED(1, false) FUSED(2, false) FUSED(3, false) FUSED(4, false)
  FUSED(5, false) FUSED(6, false) FUSED(7, false) FUSED(8, false) FUSED(9, false)
#undef FUSED
}

__global__ __launch_bounds__(256, 7) void qsim(const float* __restrict__ x,
                                               const float* __restrict__ w,
                                               float* __restrict__ out, int batch) {
  // Batch-shared fused weight matrices W = RZ(w2)*RY(w1)*RZ(w0); SU(2), so
  // only the first ROW (w00, w01) is stored.
  __shared__ float4 wmat[NL * NQ];
  int tid = threadIdx.x;
  if (tid < NL * NQ) {
    const float* wp = &w[tid * 3];
    float t0 = 0.5f * wp[0], t1 = 0.5f * wp[1], t2 = 0.5f * wp[2];
    float c1, s1; sincosf(t1, &s1, &c1);
    float cA, sA; sincosf(t0 + t2, &sA, &cA);
    float cB, sB; sincosf(t0 - t2, &sB, &cB);
    // w00 = c1*e^{-iA}; w01 = -s1*e^{+iB}
    wmat[tid] = make_float4(c1 * cA, -c1 * sA, -s1 * cB, -s1 * sB);
  }
  __syncthreads();

  int lane = tid & 63;
  int b = blockIdx.x * 4 + (tid >> 6);
  if (b >= batch) return;

  float cxv = 1.0f, sxv = 0.0f;
  if (lane < NQ) {
    float th = tanhf(x[b * NQ + lane]) * PI_F;
    sincosf(0.5f * th, &sxv, &cxv);
  }

  // Composed lane-permutation for the 5 lane-lane CNOTs.
  int srcl4;
  {
    int t = lane;
    t ^= (t >> 1) & 1;
    t ^= ((t >> 2) & 1) << 1;
    t ^= ((t >> 3) & 1) << 2;
    t ^= ((t >> 4) & 1) << 3;
    t ^= ((t >> 5) & 1) << 4;
    srcl4 = t << 2;
  }

  // Per-lane sign masks: sgn[k] = ((lane>>k)&1) << 31, for lane bit k.
  int sgn[6];
#pragma unroll
  for (int k = 0; k < 6; ++k)
    sgn[k] = (lane & (1 << k)) << (31 - k);

  v2 s[16];
  // Layer 0 single-qubit part: direct product state (|0> start), then CNOTs.
  init_product(s, wmat, cxv, sxv, lane);
  cnot_block(s, lane, srcl4);

  layer_gates<1, true>(s, wmat, cxv, sxv, sgn);
  cnot_block(s, lane, srcl4);
  layer_gates<2, true>(s, wmat, cxv, sxv, sgn);
  cnot_block(s, lane, srcl4);
  layer_gates<3, true>(s, wmat, cxv, sxv, sgn);
  cnot_block(s, lane, srcl4);
  // Layer 3's (0,9) still pending: odd regs' amps live at lane^32.

  // Measurement. q=0 (lane bit 5) sign fix for pending swap: totE - totO.
  float prob[16];
  float totE = 0.0f, totO = 0.0f;
#pragma unroll
  for (int r = 0; r < 16; ++r) {
    prob[r] = s[r].x * s[r].x + s[r].y * s[r].y;
    if (r & 1) totO += prob[r]; else totE += prob[r];
  }
  float total = totE + totO;
  float part[10];
#pragma unroll
  for (int p = 0; p < 4; ++p) {
    float acc = 0.0f;
#pragma unroll
    for (int r = 0; r < 16; ++r)
      acc += (r & (1 << p)) ? -prob[r] : prob[r];
    part[p] = acc;
  }
#pragma unroll
  for (int p = 4; p < 9; ++p)
    part[p] = (lane & (1 << (p - 4))) ? -total : total;
  {
    float d = totE - totO;             // pending xor-32 on odd regs
    part[9] = (lane & 32) ? -d : d;
  }

#pragma unroll
  for (int p = 0; p < 10; ++p) {
    float a = part[p];
    a += lxor<1>(a);
    a += lxor<2>(a);
    a += lxor<4>(a);
    a += lxor<8>(a);
    a = plsum16(a);   // xor-16 stage on VALU pipe (R11-verified sum form)
    a = plsum32(a);   // xor-32 stage on VALU pipe
    part[p] = a;
  }

  if (lane == 0) {
#pragma unroll
    for (int q = 0; q < NQ; ++q)
      out[b * NQ + q] = part[9 - q];
  }
}

}  // namespace

extern "C" void kernel_launch(void* const* d_in, const int* in_sizes, int n_in,
                              void* d_out, int out_size, void* d_ws, size_t ws_size,
                              hipStream_t stream) {
  const float* x = (const float*)d_in[0];
  const float* w = (const float*)d_in[1];
  float* out = (float*)d_out;
  int batch = in_sizes[0] / NQ;
  int blocks = (batch + 3) / 4;  // 4 waves/block, 1 batch element per wave
  qsim<<<blocks, 256, 0, stream>>>(x, w, out, batch);
}

// Round 16
// 162.088 us; speedup vs baseline: 1.0134x; 1.0134x over previous
//
#include <hip/hip_runtime.h>
#include <math.h>

namespace {

constexpr int NQ = 10;
constexpr int NL = 4;
constexpr float PI_F = 3.14159265358979323846f;

// One batch element per wave. Packed {re,im} float2 per amp. SU(2)
// exploitation: U = W*RY(a) has u11 = conj(u00), u10 = -conj(u01), so only
// u00,u01 are built; second gate row via conjugated asm variants
// (cmulc/cfmamc); lane-gate coefficient selects are single sign-bit XORs.
// Lane exchanges: DPP for masks 1,2,8; ds_swizzle for 4,16,32. Composed
// 5-CNOT lane perm -> ds_bpermute. Layer-trailing C(9->0) deferred into
// next layer's wire-0 gate. Layer 0 uses the |0> product-state shortcut.
// R16: the FINAL CNOT block (after layer-3 gates) is absorbed into the
// measurement sign masks: out_q = sum_v prob[v]*(-1)^parity(Fi.row[9-q]&v)
// where Fi = inverse of the full per-layer CNOT map (R3-HW-verified
// constants, constexpr-checked below). Saves 32 DS + ~70 VALU per wave.

typedef float v2 __attribute__((ext_vector_type(2)));

// ---- GF(2) verification of the absorbed CNOT map (compile-time only) ----
struct M10 { unsigned r[10]; };
constexpr M10 I10{{1u,2u,4u,8u,16u,32u,64u,128u,256u,512u}};
// F: full layer CNOT chain (9,8)(8,7)...(1,0)(0,9), amplitude-index form.
constexpr M10 Fm{{0x003u,0x006u,0x00Cu,0x018u,0x030u,0x060u,0x0C0u,0x180u,0x301u,0x201u}};
// Fi = F^{-1}: suffix-XOR rows.
constexpr M10 Fi{{0x3FFu,0x3FEu,0x3FCu,0x3F8u,0x3F0u,0x3E0u,0x3C0u,0x380u,0x300u,0x1FFu}};
constexpr M10 mmul(const M10& A, const M10& B) {
  M10 C{};
  for (int p = 0; p < 10; ++p) {
    unsigned v = 0;
    for (int q = 0; q < 10; ++q)
      if ((A.r[p] >> q) & 1u) v ^= B.r[q];
    C.r[p] = v;
  }
  return C;
}
constexpr bool meq(const M10& A, const M10& B) {
  for (int p = 0; p < 10; ++p) if (A.r[p] != B.r[p]) return false;
  return true;
}
static_assert(meq(mmul(Fm, Fi), I10), "Fi is not F^-1");

__device__ __forceinline__ float readlane_f(float v, int lane_const) {
  return __int_as_float(__builtin_amdgcn_readlane(__float_as_int(v), lane_const));
}
__device__ __forceinline__ float bperm_f(int addr4, float v) {
  return __int_as_float(__builtin_amdgcn_ds_bpermute(addr4, __float_as_int(v)));
}

// own + partner(lane^MASK) — direction-agnostic sum (R11-verified); used in
// the measurement butterfly only.
__device__ __forceinline__ float plsum32(float v) {
  float a = v, b = v;
  asm("v_permlane32_swap_b32 %0, %1" : "+v"(a), "+v"(b));
  return a + b;
}
__device__ __forceinline__ float plsum16(float v) {
  float a = v, b = v;
  asm("v_permlane16_swap_b32 %0, %1" : "+v"(a), "+v"(b));
  return a + b;
}

// xor-lane exchange for masks 1,2,8 (DPP) and 4,16,32 (ds_swizzle).
template<int MASK>
__device__ __forceinline__ float lxor(float v) {
  if constexpr (MASK == 1 || MASK == 2 || MASK == 8) {
    constexpr int ctrl = (MASK == 1) ? 0xB1 : (MASK == 2) ? 0x4E : 0x128;
    int i = __float_as_int(v);
    return __int_as_float(__builtin_amdgcn_update_dpp(i, i, ctrl, 0xF, 0xF, true));
  } else {
    return __shfl_xor(v, MASK, 64);
  }
}
template<int MASK>
__device__ __forceinline__ v2 lxor2(v2 v) {
  v2 r; r.x = lxor<MASK>(v.x); r.y = lxor<MASK>(v.y); return r;
}

// ---- packed complex arithmetic ({re,im} in one VGPR pair) ----
// d = u (*) a
__device__ __forceinline__ v2 cmul(v2 u, v2 a) {
  v2 d;
  asm("v_pk_mul_f32 %0, %1, %2 op_sel:[0,0] op_sel_hi:[0,1]\n\t"
      "v_pk_fma_f32 %0, %1, %2, %0 op_sel:[1,1,0] op_sel_hi:[1,0,1] neg_lo:[1,0,0]"
      : "=&v"(d) : "v"(u), "v"(a));
  return d;
}
// d = acc + u (*) a
__device__ __forceinline__ v2 cfma(v2 u, v2 a, v2 acc) {
  v2 d;
  asm("v_pk_fma_f32 %0, %1, %2, %3 op_sel:[0,0,0] op_sel_hi:[0,1,1]\n\t"
      "v_pk_fma_f32 %0, %1, %2, %0 op_sel:[1,1,0] op_sel_hi:[1,0,1] neg_lo:[1,0,0]"
      : "=&v"(d) : "v"(u), "v"(a), "v"(acc));
  return d;
}
// d = conj(u) (*) a
__device__ __forceinline__ v2 cmulc(v2 u, v2 a) {
  v2 d;
  asm("v_pk_mul_f32 %0, %1, %2 op_sel:[0,0] op_sel_hi:[0,1]\n\t"
      "v_pk_fma_f32 %0, %1, %2, %0 op_sel:[1,1,0] op_sel_hi:[1,0,1] neg_hi:[1,0,0]"
      : "=&v"(d) : "v"(u), "v"(a));
  return d;
}
// d = acc - conj(u) (*) a
__device__ __forceinline__ v2 cfmamc(v2 u, v2 a, v2 acc) {
  v2 d;
  asm("v_pk_fma_f32 %0, %1, %2, %3 op_sel:[0,0,0] op_sel_hi:[0,1,1] neg_lo:[1,0,0] neg_hi:[1,0,0]\n\t"
      "v_pk_fma_f32 %0, %1, %2, %0 op_sel:[1,1,0] op_sel_hi:[1,0,1] neg_lo:[1,0,0]"
      : "=&v"(d) : "v"(u), "v"(a), "v"(acc));
  return d;
}

// Gate on state bit P with SU(2) matrix given by u00,u01 only.
// sgn = per-lane sign mask ((lane>>bit)&1)<<31 for this gate's lane bit
// (unused for P<4). SW: pending xor-32 lane swap on odd regs consumed here
// (only legal for P==9).
template<int P, bool SW>
__device__ __forceinline__ void apply_u(v2 (&s)[16], v2 u00, v2 u01, int sgn) {
  if constexpr (P < 4) {
    constexpr int bit = 1 << P;
#pragma unroll
    for (int r = 0; r < 16; ++r) {
      if ((r & bit) == 0) {
        int r1 = r | bit;
        v2 a0 = s[r], a1 = s[r1];
        s[r]  = cfma(u01, a1, cmul(u00, a0));            // u00*a0 + u01*a1
        s[r1] = cfmamc(u01, a0, cmulc(u00, a1));         // conj(u00)*a1 - conj(u01)*a0
      }
    }
  } else {
    constexpr int mask = 1 << (P - 4);
    // hi lane: self = conj(u00), partner = -conj(u01); lo: u00, u01.
    v2 cA, cB;
    cA.x = u00.x;
    cA.y = __int_as_float(__float_as_int(u00.y) ^ sgn);
    cB.x = __int_as_float(__float_as_int(u01.x) ^ sgn);
    cB.y = u01.y;
#pragma unroll
    for (int r = 0; r < 16; ++r) {
      v2 p = lxor2<mask>(s[r]);
      if constexpr (SW) {
        if (r & 1) { s[r] = cfma(cA, p, cmul(cB, s[r])); continue; }
      }
      s[r] = cfma(cB, p, cmul(cA, s[r]));
    }
  }
}

// CNOT chain: (9,8)(8,7)(7,6)(6,5)(5,4) composed bpermute | (4,3) cndmask |
// (3,2)(2,1)(1,0) reg swaps | (0,9) DEFERRED.
__device__ __forceinline__ void cnot_block(v2 (&s)[16], int lane, int srcl4) {
#pragma unroll
  for (int r = 0; r < 16; ++r) {
    s[r].x = bperm_f(srcl4, s[r].x);
    s[r].y = bperm_f(srcl4, s[r].y);
  }
  bool ctrl = (lane & 1) != 0;
#pragma unroll
  for (int r = 0; r < 8; ++r) {
    int r1 = r | 8;
    v2 t0 = s[r], t1 = s[r1];
    s[r]  = ctrl ? t1 : t0;
    s[r1] = ctrl ? t0 : t1;
  }
#pragma unroll
  for (int r = 8; r < 12; ++r) { v2 t = s[r]; s[r] = s[r | 4]; s[r | 4] = t; }
  {
    const int rs[4] = {4, 5, 12, 13};
#pragma unroll
    for (int k = 0; k < 4; ++k) {
      int r = rs[k];
      v2 t = s[r]; s[r] = s[r | 2]; s[r | 2] = t;
    }
  }
#pragma unroll
  for (int r = 2; r < 16; r += 4) { v2 t = s[r]; s[r] = s[r | 1]; s[r | 1] = t; }
}

// Layer 0 on |0>: product state. Wire w (0..5) -> lane bit (5-w);
// wires 6..9 -> reg bits 3..0. amp = prod of column-0 entries
// (col0 of U = {u00, u10 = -conj(u01)}).
__device__ __forceinline__ void init_product(v2 (&s)[16], const float4* wmat,
                                             float cx, float sx, int lane) {
  v2 u0, u1;
#define C0(i) { float4 wa = wmat[(i)]; \
    v2 wa0 = {wa.x, wa.y}, wa1 = {wa.z, wa.w}; \
    float ca = readlane_f(cx, (i)), sa = readlane_f(sx, (i)); \
    u0 = ca * wa0 + sa * wa1; \
    v2 t01 = ca * wa1 - sa * wa0; \
    u1.x = -t01.x; u1.y = t01.y; }
  v2 f;
  C0(0); f = (lane & 32) ? u1 : u0;
  C0(1); f = cmul((lane & 16) ? u1 : u0, f);
  C0(2); f = cmul((lane & 8) ? u1 : u0, f);
  C0(3); f = cmul((lane & 4) ? u1 : u0, f);
  C0(4); f = cmul((lane & 2) ? u1 : u0, f);
  C0(5); f = cmul((lane & 1) ? u1 : u0, f);
  v2 q6_0, q6_1, q7_0, q7_1, q8_0, q8_1, q9_0, q9_1;
  C0(6); q6_0 = u0; q6_1 = u1;
  C0(7); q7_0 = u0; q7_1 = u1;
  C0(8); q8_0 = u0; q8_1 = u1;
  C0(9); q9_0 = u0; q9_1 = u1;
#undef C0
  v2 qa0 = cmul(q8_0, q9_0), qa1 = cmul(q8_0, q9_1);
  v2 qa2 = cmul(q8_1, q9_0), qa3 = cmul(q8_1, q9_1);
  v2 qb0 = cmul(q6_0, q7_0), qb1 = cmul(q6_0, q7_1);
  v2 qb2 = cmul(q6_1, q7_0), qb3 = cmul(q6_1, q7_1);
  v2 fa0 = cmul(qa0, f), fa1 = cmul(qa1, f), fa2 = cmul(qa2, f), fa3 = cmul(qa3, f);
  s[0]  = cmul(qb0, fa0); s[1]  = cmul(qb0, fa1); s[2]  = cmul(qb0, fa2); s[3]  = cmul(qb0, fa3);
  s[4]  = cmul(qb1, fa0); s[5]  = cmul(qb1, fa1); s[6]  = cmul(qb1, fa2); s[7]  = cmul(qb1, fa3);
  s[8]  = cmul(qb2, fa0); s[9]  = cmul(qb2, fa1); s[10] = cmul(qb2, fa2); s[11] = cmul(qb2, fa3);
  s[12] = cmul(qb3, fa0); s[13] = cmul(qb3, fa1); s[14] = cmul(qb3, fa2); s[15] = cmul(qb3, fa3);
}

template<int L, bool PEND>
__device__ __forceinline__ void layer_gates(v2 (&s)[16], const float4* wmat,
                                            float cxv, float sxv,
                                            const int (&sgn)[6]) {
#define FUSED(i, SW) { \
    float4 wa = wmat[L * NQ + (i)]; \
    float ca = readlane_f(cxv, (i)); \
    float sa = readlane_f(sxv, (i)); \
    v2 wa0 = {wa.x, wa.y}, wa1 = {wa.z, wa.w}; \
    v2 u00 = ca * wa0 + sa * wa1, u01 = ca * wa1 - sa * wa0; \
    apply_u<9 - (i), SW>(s, u00, u01, ((i) < 6) ? sgn[5 - (i)] : 0); }
  FUSED(0, PEND)            // wire0 = bit9 = lane xor 32; consumes pending swap
  FUSED(1, false) FUSED(2, false) FUSED(3, false) FUSED(4, false)
  FUSED(5, false) FUSED(6, false) FUSED(7, false) FUSED(8, false) FUSED(9, false)
#undef FUSED
}

__global__ __launch_bounds__(256, 7) void qsim(const float* __restrict__ x,
                                               const float* __restrict__ w,
                                               float* __restrict__ out, int batch) {
  // Batch-shared fused weight matrices W = RZ(w2)*RY(w1)*RZ(w0); SU(2), so
  // only the first ROW (w00, w01) is stored.
  __shared__ float4 wmat[NL * NQ];
  int tid = threadIdx.x;
  if (tid < NL * NQ) {
    const float* wp = &w[tid * 3];
    float t0 = 0.5f * wp[0], t1 = 0.5f * wp[1], t2 = 0.5f * wp[2];
    float c1, s1; sincosf(t1, &s1, &c1);
    float cA, sA; sincosf(t0 + t2, &sA, &cA);
    float cB, sB; sincosf(t0 - t2, &sB, &cB);
    // w00 = c1*e^{-iA}; w01 = -s1*e^{+iB}
    wmat[tid] = make_float4(c1 * cA, -c1 * sA, -s1 * cB, -s1 * sB);
  }
  __syncthreads();

  int lane = tid & 63;
  int b = blockIdx.x * 4 + (tid >> 6);
  if (b >= batch) return;

  float cxv = 1.0f, sxv = 0.0f;
  if (lane < NQ) {
    float th = tanhf(x[b * NQ + lane]) * PI_F;
    sincosf(0.5f * th, &sxv, &cxv);
  }

  // Composed lane-permutation for the 5 lane-lane CNOTs.
  int srcl4;
  {
    int t = lane;
    t ^= (t >> 1) & 1;
    t ^= ((t >> 2) & 1) << 1;
    t ^= ((t >> 3) & 1) << 2;
    t ^= ((t >> 4) & 1) << 3;
    t ^= ((t >> 5) & 1) << 4;
    srcl4 = t << 2;
  }

  // Per-lane sign masks: sgn[k] = ((lane>>k)&1) << 31, for lane bit k.
  int sgn[6];
#pragma unroll
  for (int k = 0; k < 6; ++k)
    sgn[k] = (lane & (1 << k)) << (31 - k);

  v2 s[16];
  // Layer 0 single-qubit part: direct product state (|0> start), then CNOTs.
  init_product(s, wmat, cxv, sxv, lane);
  cnot_block(s, lane, srcl4);

  layer_gates<1, true>(s, wmat, cxv, sxv, sgn);
  cnot_block(s, lane, srcl4);
  layer_gates<2, true>(s, wmat, cxv, sxv, sgn);
  cnot_block(s, lane, srcl4);
  layer_gates<3, true>(s, wmat, cxv, sxv, sgn);
  // Layer 3's FULL CNOT chain (incl. its (0,9)) is absorbed into the
  // measurement sign masks below via Fi = F^{-1}.

  // Measurement: out_q = sum_v prob[v] * (-1)^{parity(Fi.row[9-q] & v)},
  // storage v = (lane<<4)|r; Fi rows (verified above):
  //   p: 0     1     2     3     4     5     6     7     8     9
  //   M: 3FF   3FE   3FC   3F8   3F0   3E0   3C0   380   300   1FF
  // reg-part masks: F,E,C,8,0,0,0,0,0,F ; lane-part: suffix masks.
  float prob[16];
#pragma unroll
  for (int r = 0; r < 16; ++r)
    prob[r] = s[r].x * s[r].x + s[r].y * s[r].y;

  float S0 = 0.0f, S8 = 0.0f, SC = 0.0f, SE = 0.0f, SF = 0.0f;
#pragma unroll
  for (int r = 0; r < 16; ++r) {
    float pr = prob[r];
    S0 += pr;
    S8 += (__builtin_popcount(r & 0x8) & 1) ? -pr : pr;
    SC += (__builtin_popcount(r & 0xC) & 1) ? -pr : pr;
    SE += (__builtin_popcount(r & 0xE) & 1) ? -pr : pr;
    SF += (__builtin_popcount(r & 0xF) & 1) ? -pr : pr;
  }

  // Lane suffix parities.
  int l0 = lane & 1, l1 = (lane >> 1) & 1, l2 = (lane >> 2) & 1;
  int l3 = (lane >> 3) & 1, l4 = (lane >> 4) & 1, l5 = (lane >> 5) & 1;
  int p30 = l4 ^ l5;        // mask 0x30
  int p38 = p30 ^ l3;       // 0x38
  int p3C = p38 ^ l2;       // 0x3C
  int p3E = p3C ^ l1;       // 0x3E
  int p3F = p3E ^ l0;       // 0x3F
  int p1F = p3F ^ l5;       // 0x1F

  float part[10];
  part[0] = p3F ? -SF : SF;
  part[1] = p3F ? -SE : SE;
  part[2] = p3F ? -SC : SC;
  part[3] = p3F ? -S8 : S8;
  part[4] = p3F ? -S0 : S0;
  part[5] = p3E ? -S0 : S0;
  part[6] = p3C ? -S0 : S0;
  part[7] = p38 ? -S0 : S0;
  part[8] = p30 ? -S0 : S0;
  part[9] = p1F ? -SF : SF;

#pragma unroll
  for (int p = 0; p < 10; ++p) {
    float a = part[p];
    a += lxor<1>(a);
    a += lxor<2>(a);
    a += lxor<4>(a);
    a += lxor<8>(a);
    a = plsum16(a);   // xor-16 stage on VALU pipe (R11-verified sum form)
    a = plsum32(a);   // xor-32 stage on VALU pipe
    part[p] = a;
  }

  if (lane == 0) {
#pragma unroll
    for (int q = 0; q < NQ; ++q)
      out[b * NQ + q] = part[9 - q];
  }
}

}  // namespace

extern "C" void kernel_launch(void* const* d_in, const int* in_sizes, int n_in,
                              void* d_out, int out_size, void* d_ws, size_t ws_size,
                              hipStream_t stream) {
  const float* x = (const float*)d_in[0];
  const float* w = (const float*)d_in[1];
  float* out = (float*)d_out;
  int batch = in_sizes[0] / NQ;
  int blocks = (batch + 3) / 4;  // 4 waves/block, 1 batch element per wave
  qsim<<<blocks, 256, 0, stream>>>(x, w, out, batch);
}

// Round 17
// 137.197 us; speedup vs baseline: 1.1973x; 1.1814x over previous
//
#include <hip/hip_runtime.h>
#include <math.h>

namespace {

constexpr int NQ = 10;
constexpr int NL = 4;
constexpr float PI_F = 3.14159265358979323846f;

// One batch element per wave. Each complex amp packed as f16 {re=lo, im=hi}
// in ONE 32-bit VGPR (carrier type: float). Complex math via v_pk_fma_f16
// with the SAME VOP3P op_sel/neg modifiers as the verified f32 version
// (R14/R15/R16) — f16 pk ops run at 2x the f32 pk rate AND halve every
// lane-exchange (one b32 per amp). SU(2): only u00,u01 built; second row
// via conjugated variants; lane-gate coefficient selects are sign-bit XORs
// (hi-half bit31 for im, lo-half bit15 for re). Conversions f32->f16 use
// RNE (v_cvt_f16_f32 + v_pack_b32_f16), avoiding RTZ's systematic
// unitarity shrink. prob = v_dot2_f32_f16(s,s,0) — exact f32 accumulate.
// Structure otherwise identical to R16 (verified): DPP masks 1,2,8;
// ds_swizzle 4,16,32; composed 5-CNOT bpermute; C(9->0) deferred; final
// CNOT chain absorbed into measurement sign masks (Fi rows).

typedef float v2 __attribute__((ext_vector_type(2)));

// ---- GF(2) verification of the absorbed CNOT map (compile-time only) ----
struct M10 { unsigned r[10]; };
constexpr M10 I10{{1u,2u,4u,8u,16u,32u,64u,128u,256u,512u}};
constexpr M10 Fm{{0x003u,0x006u,0x00Cu,0x018u,0x030u,0x060u,0x0C0u,0x180u,0x301u,0x201u}};
constexpr M10 Fi{{0x3FFu,0x3FEu,0x3FCu,0x3F8u,0x3F0u,0x3E0u,0x3C0u,0x380u,0x300u,0x1FFu}};
constexpr M10 mmul(const M10& A, const M10& B) {
  M10 C{};
  for (int p = 0; p < 10; ++p) {
    unsigned v = 0;
    for (int q = 0; q < 10; ++q)
      if ((A.r[p] >> q) & 1u) v ^= B.r[q];
    C.r[p] = v;
  }
  return C;
}
constexpr bool meq(const M10& A, const M10& B) {
  for (int p = 0; p < 10; ++p) if (A.r[p] != B.r[p]) return false;
  return true;
}
static_assert(meq(mmul(Fm, Fi), I10), "Fi is not F^-1");

__device__ __forceinline__ float readlane_f(float v, int lane_const) {
  return __int_as_float(__builtin_amdgcn_readlane(__float_as_int(v), lane_const));
}
__device__ __forceinline__ float bperm_f(int addr4, float v) {
  return __int_as_float(__builtin_amdgcn_ds_bpermute(addr4, __float_as_int(v)));
}
__device__ __forceinline__ float fxor(float v, int m) {
  return __int_as_float(__float_as_int(v) ^ m);
}

// own + partner — direction-agnostic permlane sum (R11-verified); used in
// the measurement butterfly only.
__device__ __forceinline__ float plsum32(float v) {
  float a = v, b = v;
  asm("v_permlane32_swap_b32 %0, %1" : "+v"(a), "+v"(b));
  return a + b;
}
__device__ __forceinline__ float plsum16(float v) {
  float a = v, b = v;
  asm("v_permlane16_swap_b32 %0, %1" : "+v"(a), "+v"(b));
  return a + b;
}

// xor-lane exchange for masks 1,2,8 (DPP) and 4,16,32 (ds_swizzle).
template<int MASK>
__device__ __forceinline__ float lxor(float v) {
  if constexpr (MASK == 1 || MASK == 2 || MASK == 8) {
    constexpr int ctrl = (MASK == 1) ? 0xB1 : (MASK == 2) ? 0x4E : 0x128;
    int i = __float_as_int(v);
    return __int_as_float(__builtin_amdgcn_update_dpp(i, i, ctrl, 0xF, 0xF, true));
  } else {
    return __shfl_xor(v, MASK, 64);
  }
}

// ---- packed complex f16 arithmetic ({re,im} in ONE VGPR) ----
// d = u (*) a
__device__ __forceinline__ float hcmul(float u, float a) {
  float d;
  asm("v_pk_mul_f16 %0, %1, %2 op_sel:[0,0] op_sel_hi:[0,1]\n\t"
      "v_pk_fma_f16 %0, %1, %2, %0 op_sel:[1,1,0] op_sel_hi:[1,0,1] neg_lo:[1,0,0]"
      : "=&v"(d) : "v"(u), "v"(a));
  return d;
}
// d = acc + u (*) a
__device__ __forceinline__ float hcfma(float u, float a, float acc) {
  float d;
  asm("v_pk_fma_f16 %0, %1, %2, %3 op_sel:[0,0,0] op_sel_hi:[0,1,1]\n\t"
      "v_pk_fma_f16 %0, %1, %2, %0 op_sel:[1,1,0] op_sel_hi:[1,0,1] neg_lo:[1,0,0]"
      : "=&v"(d) : "v"(u), "v"(a), "v"(acc));
  return d;
}
// d = conj(u) (*) a
__device__ __forceinline__ float hcmulc(float u, float a) {
  float d;
  asm("v_pk_mul_f16 %0, %1, %2 op_sel:[0,0] op_sel_hi:[0,1]\n\t"
      "v_pk_fma_f16 %0, %1, %2, %0 op_sel:[1,1,0] op_sel_hi:[1,0,1] neg_hi:[1,0,0]"
      : "=&v"(d) : "v"(u), "v"(a));
  return d;
}
// d = acc - conj(u) (*) a
__device__ __forceinline__ float hcfmamc(float u, float a, float acc) {
  float d;
  asm("v_pk_fma_f16 %0, %1, %2, %3 op_sel:[0,0,0] op_sel_hi:[0,1,1] neg_lo:[1,0,0] neg_hi:[1,0,0]\n\t"
      "v_pk_fma_f16 %0, %1, %2, %0 op_sel:[1,1,0] op_sel_hi:[1,0,1] neg_lo:[1,0,0]"
      : "=&v"(d) : "v"(u), "v"(a), "v"(acc));
  return d;
}
// RNE pack: two f32 -> packed f16 pair.
__device__ __forceinline__ float pack16(float x, float y) {
  float lo, hi, d;
  asm("v_cvt_f16_f32 %0, %1" : "=v"(lo) : "v"(x));
  asm("v_cvt_f16_f32 %0, %1" : "=v"(hi) : "v"(y));
  asm("v_pack_b32_f16 %0, %1, %2" : "=v"(d) : "v"(lo), "v"(hi));
  return d;
}
// re^2 + im^2 accumulated in f32.
__device__ __forceinline__ float hdot2(float s, float acc) {
  float d;
  asm("v_dot2_f32_f16 %0, %1, %1, %2" : "=v"(d) : "v"(s), "v"(acc));
  return d;
}

// Gate on state bit P; u00p,u01p = packed f16 first row. sgnh/sgnl: per-lane
// sign masks (bit31 / bit15) for this gate's lane bit (0 for P<4).
// SW: pending xor-32 lane swap on odd regs consumed here (P==9 only).
template<int P, bool SW>
__device__ __forceinline__ void apply_u(float (&s)[16], float u00p, float u01p,
                                        int sgnh, int sgnl) {
  if constexpr (P < 4) {
    constexpr int bit = 1 << P;
#pragma unroll
    for (int r = 0; r < 16; ++r) {
      if ((r & bit) == 0) {
        int r1 = r | bit;
        float a0 = s[r], a1 = s[r1];
        s[r]  = hcfma(u01p, a1, hcmul(u00p, a0));     // u00*a0 + u01*a1
        s[r1] = hcfmamc(u01p, a0, hcmulc(u00p, a1));  // conj(u00)*a1 - conj(u01)*a0
      }
    }
  } else {
    constexpr int mask = 1 << (P - 4);
    // hi lane: self = conj(u00) (flip im=hi sign), partner = -conj(u01)
    // (flip re=lo sign); lo lane: u00, u01.
    float cA = fxor(u00p, sgnh);
    float cB = fxor(u01p, sgnl);
#pragma unroll
    for (int r = 0; r < 16; ++r) {
      float p = lxor<mask>(s[r]);
      if constexpr (SW) {
        if (r & 1) { s[r] = hcfma(cA, p, hcmul(cB, s[r])); continue; }
      }
      s[r] = hcfma(cB, p, hcmul(cA, s[r]));
    }
  }
}

// CNOT chain: (9,8)(8,7)(7,6)(6,5)(5,4) composed bpermute | (4,3) cndmask |
// (3,2)(2,1)(1,0) reg swaps | (0,9) DEFERRED.
__device__ __forceinline__ void cnot_block(float (&s)[16], int lane, int srcl4) {
#pragma unroll
  for (int r = 0; r < 16; ++r)
    s[r] = bperm_f(srcl4, s[r]);
  bool ctrl = (lane & 1) != 0;
#pragma unroll
  for (int r = 0; r < 8; ++r) {
    int r1 = r | 8;
    float t0 = s[r], t1 = s[r1];
    s[r]  = ctrl ? t1 : t0;
    s[r1] = ctrl ? t0 : t1;
  }
#pragma unroll
  for (int r = 8; r < 12; ++r) { float t = s[r]; s[r] = s[r | 4]; s[r | 4] = t; }
  {
    const int rs[4] = {4, 5, 12, 13};
#pragma unroll
    for (int k = 0; k < 4; ++k) {
      int r = rs[k];
      float t = s[r]; s[r] = s[r | 2]; s[r | 2] = t;
    }
  }
#pragma unroll
  for (int r = 2; r < 16; r += 4) { float t = s[r]; s[r] = s[r | 1]; s[r | 1] = t; }
}

// Layer 0 on |0>: product state. Wire w (0..5) -> lane bit (5-w);
// wires 6..9 -> reg bits 3..0. amp = prod of column-0 entries
// (col0 = {u00, -conj(u01)}), built f32 then packed f16.
__device__ __forceinline__ void init_product(float (&s)[16], const float4* wmat,
                                             float cx, float sx, int lane) {
  float u0p, u1p;
#define C0(i) { float4 wa = wmat[(i)]; \
    v2 wa0 = {wa.x, wa.y}, wa1 = {wa.z, wa.w}; \
    float ca = readlane_f(cx, (i)), sa = readlane_f(sx, (i)); \
    v2 u0 = ca * wa0 + sa * wa1; \
    v2 t01 = ca * wa1 - sa * wa0; \
    u0p = pack16(u0.x, u0.y); \
    u1p = pack16(-t01.x, t01.y); }
  float f;
  C0(0); f = (lane & 32) ? u1p : u0p;
  C0(1); f = hcmul((lane & 16) ? u1p : u0p, f);
  C0(2); f = hcmul((lane & 8) ? u1p : u0p, f);
  C0(3); f = hcmul((lane & 4) ? u1p : u0p, f);
  C0(4); f = hcmul((lane & 2) ? u1p : u0p, f);
  C0(5); f = hcmul((lane & 1) ? u1p : u0p, f);
  float q6_0, q6_1, q7_0, q7_1, q8_0, q8_1, q9_0, q9_1;
  C0(6); q6_0 = u0p; q6_1 = u1p;
  C0(7); q7_0 = u0p; q7_1 = u1p;
  C0(8); q8_0 = u0p; q8_1 = u1p;
  C0(9); q9_0 = u0p; q9_1 = u1p;
#undef C0
  float qa0 = hcmul(q8_0, q9_0), qa1 = hcmul(q8_0, q9_1);
  float qa2 = hcmul(q8_1, q9_0), qa3 = hcmul(q8_1, q9_1);
  float qb0 = hcmul(q6_0, q7_0), qb1 = hcmul(q6_0, q7_1);
  float qb2 = hcmul(q6_1, q7_0), qb3 = hcmul(q6_1, q7_1);
  float fa0 = hcmul(qa0, f), fa1 = hcmul(qa1, f), fa2 = hcmul(qa2, f), fa3 = hcmul(qa3, f);
  s[0]  = hcmul(qb0, fa0); s[1]  = hcmul(qb0, fa1); s[2]  = hcmul(qb0, fa2); s[3]  = hcmul(qb0, fa3);
  s[4]  = hcmul(qb1, fa0); s[5]  = hcmul(qb1, fa1); s[6]  = hcmul(qb1, fa2); s[7]  = hcmul(qb1, fa3);
  s[8]  = hcmul(qb2, fa0); s[9]  = hcmul(qb2, fa1); s[10] = hcmul(qb2, fa2); s[11] = hcmul(qb2, fa3);
  s[12] = hcmul(qb3, fa0); s[13] = hcmul(qb3, fa1); s[14] = hcmul(qb3, fa2); s[15] = hcmul(qb3, fa3);
}

template<int L, bool PEND>
__device__ __forceinline__ void layer_gates(float (&s)[16], const float4* wmat,
                                            float cxv, float sxv,
                                            const int (&sgnh)[6], const int (&sgnl)[6]) {
#define FUSED(i, SW) { \
    float4 wa = wmat[L * NQ + (i)]; \
    float ca = readlane_f(cxv, (i)); \
    float sa = readlane_f(sxv, (i)); \
    v2 wa0 = {wa.x, wa.y}, wa1 = {wa.z, wa.w}; \
    v2 u00 = ca * wa0 + sa * wa1, u01 = ca * wa1 - sa * wa0; \
    float u00p = pack16(u00.x, u00.y), u01p = pack16(u01.x, u01.y); \
    apply_u<9 - (i), SW>(s, u00p, u01p, \
        ((i) < 6) ? sgnh[5 - (i)] : 0, ((i) < 6) ? sgnl[5 - (i)] : 0); }
  FUSED(0, PEND)            // wire0 = bit9 = lane xor 32; consumes pending swap
  FUSED(1, false) FUSED(2, false) FUSED(3, false) FUSED(4, false)
  FUSED(5, false) FUSED(6, false) FUSED(7, false) FUSED(8, false) FUSED(9, false)
#undef FUSED
}

__global__ __launch_bounds__(256, 7) void qsim(const float* __restrict__ x,
                                               const float* __restrict__ w,
                                               float* __restrict__ out, int batch) {
  // Batch-shared fused weight matrices W = RZ(w2)*RY(w1)*RZ(w0); SU(2), so
  // only the first ROW (w00, w01) is stored (f32 for accuracy).
  __shared__ float4 wmat[NL * NQ];
  int tid = threadIdx.x;
  if (tid < NL * NQ) {
    const float* wp = &w[tid * 3];
    float t0 = 0.5f * wp[0], t1 = 0.5f * wp[1], t2 = 0.5f * wp[2];
    float c1, s1; sincosf(t1, &s1, &c1);
    float cA, sA; sincosf(t0 + t2, &sA, &cA);
    float cB, sB; sincosf(t0 - t2, &sB, &cB);
    wmat[tid] = make_float4(c1 * cA, -c1 * sA, -s1 * cB, -s1 * sB);
  }
  __syncthreads();

  int lane = tid & 63;
  int b = blockIdx.x * 4 + (tid >> 6);
  if (b >= batch) return;

  float cxv = 1.0f, sxv = 0.0f;
  if (lane < NQ) {
    float th = tanhf(x[b * NQ + lane]) * PI_F;
    sincosf(0.5f * th, &sxv, &cxv);
  }

  // Composed lane-permutation for the 5 lane-lane CNOTs.
  int srcl4;
  {
    int t = lane;
    t ^= (t >> 1) & 1;
    t ^= ((t >> 2) & 1) << 1;
    t ^= ((t >> 3) & 1) << 2;
    t ^= ((t >> 4) & 1) << 3;
    t ^= ((t >> 5) & 1) << 4;
    srcl4 = t << 2;
  }

  // Per-lane sign masks for lane bit k: hi-half (im) bit31, lo-half (re) bit15.
  int sgnh[6], sgnl[6];
#pragma unroll
  for (int k = 0; k < 6; ++k) {
    int bit = (lane >> k) & 1;
    sgnh[k] = bit << 31;
    sgnl[k] = bit << 15;
  }

  float s[16];
  // Layer 0 single-qubit part: direct product state (|0> start), then CNOTs.
  init_product(s, wmat, cxv, sxv, lane);
  cnot_block(s, lane, srcl4);

  layer_gates<1, true>(s, wmat, cxv, sxv, sgnh, sgnl);
  cnot_block(s, lane, srcl4);
  layer_gates<2, true>(s, wmat, cxv, sxv, sgnh, sgnl);
  cnot_block(s, lane, srcl4);
  layer_gates<3, true>(s, wmat, cxv, sxv, sgnh, sgnl);
  // Layer 3's FULL CNOT chain absorbed into measurement sign masks (Fi).

  // prob in exact f32 via v_dot2_f32_f16.
  float prob[16];
#pragma unroll
  for (int r = 0; r < 16; ++r)
    prob[r] = hdot2(s[r], 0.0f);

  float S0 = 0.0f, S8 = 0.0f, SC = 0.0f, SE = 0.0f, SF = 0.0f;
#pragma unroll
  for (int r = 0; r < 16; ++r) {
    float pr = prob[r];
    S0 += pr;
    S8 += (__builtin_popcount(r & 0x8) & 1) ? -pr : pr;
    SC += (__builtin_popcount(r & 0xC) & 1) ? -pr : pr;
    SE += (__builtin_popcount(r & 0xE) & 1) ? -pr : pr;
    SF += (__builtin_popcount(r & 0xF) & 1) ? -pr : pr;
  }

  // Lane suffix parities (Fi rows).
  int l0 = lane & 1, l1 = (lane >> 1) & 1, l2 = (lane >> 2) & 1;
  int l3 = (lane >> 3) & 1, l4 = (lane >> 4) & 1, l5 = (lane >> 5) & 1;
  int p30 = l4 ^ l5;
  int p38 = p30 ^ l3;
  int p3C = p38 ^ l2;
  int p3E = p3C ^ l1;
  int p3F = p3E ^ l0;
  int p1F = p3F ^ l5;

  float part[10];
  part[0] = p3F ? -SF : SF;
  part[1] = p3F ? -SE : SE;
  part[2] = p3F ? -SC : SC;
  part[3] = p3F ? -S8 : S8;
  part[4] = p3F ? -S0 : S0;
  part[5] = p3E ? -S0 : S0;
  part[6] = p3C ? -S0 : S0;
  part[7] = p38 ? -S0 : S0;
  part[8] = p30 ? -S0 : S0;
  part[9] = p1F ? -SF : SF;

#pragma unroll
  for (int p = 0; p < 10; ++p) {
    float a = part[p];
    a += lxor<1>(a);
    a += lxor<2>(a);
    a += lxor<4>(a);
    a += lxor<8>(a);
    a = plsum16(a);
    a = plsum32(a);
    part[p] = a;
  }

  if (lane == 0) {
#pragma unroll
    for (int q = 0; q < NQ; ++q)
      out[b * NQ + q] = part[9 - q];
  }
}

}  // namespace

extern "C" void kernel_launch(void* const* d_in, const int* in_sizes, int n_in,
                              void* d_out, int out_size, void* d_ws, size_t ws_size,
                              hipStream_t stream) {
  const float* x = (const float*)d_in[0];
  const float* w = (const float*)d_in[1];
  float* out = (float*)d_out;
  int batch = in_sizes[0] / NQ;
  int blocks = (batch + 3) / 4;  // 4 waves/block, 1 batch element per wave
  qsim<<<blocks, 256, 0, stream>>>(x, w, out, batch);
}

// Round 20
// 137.138 us; speedup vs baseline: 1.1978x; 1.0004x over previous
//
#include <hip/hip_runtime.h>
#include <math.h>

namespace {

constexpr int NQ = 10;
constexpr int NL = 4;
constexpr float PI_F = 3.14159265358979323846f;

// One batch element per wave. Each complex amp packed as f16 {re=lo, im=hi}
// in ONE 32-bit VGPR (carrier type: float). Complex math via v_pk_fma_f16
// with the SAME VOP3P op_sel/neg modifiers as the verified f32 version
// (R14/R15/R16) — f16 pk ops run at 2x the f32 pk rate AND halve every
// lane-exchange (one b32 per amp). SU(2): only u00,u01 built; second row
// via conjugated variants; lane-gate coefficient selects are sign-bit XORs
// (hi-half bit31 for im, lo-half bit15 for re). Conversions f32->f16 use
// RNE (v_cvt_f16_f32 + v_pack_b32_f16), avoiding RTZ's systematic
// unitarity shrink. prob = v_dot2_f32_f16(s,s,0) — exact f32 accumulate.
// Structure otherwise identical to R16 (verified): DPP masks 1,2,8;
// ds_swizzle 4,16,32; composed 5-CNOT bpermute; C(9->0) deferred; final
// CNOT chain absorbed into measurement sign masks (Fi rows).
// R20 NOTE: this is the verified R17 kernel (99.8us, absmax 3.9e-3),
// reverted verbatim after the 2-elem/wave variants (R18/R19) failed
// correctness for reasons not localizable from source.

typedef float v2 __attribute__((ext_vector_type(2)));

// ---- GF(2) verification of the absorbed CNOT map (compile-time only) ----
struct M10 { unsigned r[10]; };
constexpr M10 I10{{1u,2u,4u,8u,16u,32u,64u,128u,256u,512u}};
constexpr M10 Fm{{0x003u,0x006u,0x00Cu,0x018u,0x030u,0x060u,0x0C0u,0x180u,0x301u,0x201u}};
constexpr M10 Fi{{0x3FFu,0x3FEu,0x3FCu,0x3F8u,0x3F0u,0x3E0u,0x3C0u,0x380u,0x300u,0x1FFu}};
constexpr M10 mmul(const M10& A, const M10& B) {
  M10 C{};
  for (int p = 0; p < 10; ++p) {
    unsigned v = 0;
    for (int q = 0; q < 10; ++q)
      if ((A.r[p] >> q) & 1u) v ^= B.r[q];
    C.r[p] = v;
  }
  return C;
}
constexpr bool meq(const M10& A, const M10& B) {
  for (int p = 0; p < 10; ++p) if (A.r[p] != B.r[p]) return false;
  return true;
}
static_assert(meq(mmul(Fm, Fi), I10), "Fi is not F^-1");

__device__ __forceinline__ float readlane_f(float v, int lane_const) {
  return __int_as_float(__builtin_amdgcn_readlane(__float_as_int(v), lane_const));
}
__device__ __forceinline__ float bperm_f(int addr4, float v) {
  return __int_as_float(__builtin_amdgcn_ds_bpermute(addr4, __float_as_int(v)));
}
__device__ __forceinline__ float fxor(float v, int m) {
  return __int_as_float(__float_as_int(v) ^ m);
}

// own + partner — direction-agnostic permlane sum (R11-verified); used in
// the measurement butterfly only.
__device__ __forceinline__ float plsum32(float v) {
  float a = v, b = v;
  asm("v_permlane32_swap_b32 %0, %1" : "+v"(a), "+v"(b));
  return a + b;
}
__device__ __forceinline__ float plsum16(float v) {
  float a = v, b = v;
  asm("v_permlane16_swap_b32 %0, %1" : "+v"(a), "+v"(b));
  return a + b;
}

// xor-lane exchange for masks 1,2,8 (DPP) and 4,16,32 (ds_swizzle).
template<int MASK>
__device__ __forceinline__ float lxor(float v) {
  if constexpr (MASK == 1 || MASK == 2 || MASK == 8) {
    constexpr int ctrl = (MASK == 1) ? 0xB1 : (MASK == 2) ? 0x4E : 0x128;
    int i = __float_as_int(v);
    return __int_as_float(__builtin_amdgcn_update_dpp(i, i, ctrl, 0xF, 0xF, true));
  } else {
    return __shfl_xor(v, MASK, 64);
  }
}

// ---- packed complex f16 arithmetic ({re,im} in ONE VGPR) ----
// d = u (*) a
__device__ __forceinline__ float hcmul(float u, float a) {
  float d;
  asm("v_pk_mul_f16 %0, %1, %2 op_sel:[0,0] op_sel_hi:[0,1]\n\t"
      "v_pk_fma_f16 %0, %1, %2, %0 op_sel:[1,1,0] op_sel_hi:[1,0,1] neg_lo:[1,0,0]"
      : "=&v"(d) : "v"(u), "v"(a));
  return d;
}
// d = acc + u (*) a
__device__ __forceinline__ float hcfma(float u, float a, float acc) {
  float d;
  asm("v_pk_fma_f16 %0, %1, %2, %3 op_sel:[0,0,0] op_sel_hi:[0,1,1]\n\t"
      "v_pk_fma_f16 %0, %1, %2, %0 op_sel:[1,1,0] op_sel_hi:[1,0,1] neg_lo:[1,0,0]"
      : "=&v"(d) : "v"(u), "v"(a), "v"(acc));
  return d;
}
// d = conj(u) (*) a
__device__ __forceinline__ float hcmulc(float u, float a) {
  float d;
  asm("v_pk_mul_f16 %0, %1, %2 op_sel:[0,0] op_sel_hi:[0,1]\n\t"
      "v_pk_fma_f16 %0, %1, %2, %0 op_sel:[1,1,0] op_sel_hi:[1,0,1] neg_hi:[1,0,0]"
      : "=&v"(d) : "v"(u), "v"(a));
  return d;
}
// d = acc - conj(u) (*) a
__device__ __forceinline__ float hcfmamc(float u, float a, float acc) {
  float d;
  asm("v_pk_fma_f16 %0, %1, %2, %3 op_sel:[0,0,0] op_sel_hi:[0,1,1] neg_lo:[1,0,0] neg_hi:[1,0,0]\n\t"
      "v_pk_fma_f16 %0, %1, %2, %0 op_sel:[1,1,0] op_sel_hi:[1,0,1] neg_lo:[1,0,0]"
      : "=&v"(d) : "v"(u), "v"(a), "v"(acc));
  return d;
}
// RNE pack: two f32 -> packed f16 pair.
__device__ __forceinline__ float pack16(float x, float y) {
  float lo, hi, d;
  asm("v_cvt_f16_f32 %0, %1" : "=v"(lo) : "v"(x));
  asm("v_cvt_f16_f32 %0, %1" : "=v"(hi) : "v"(y));
  asm("v_pack_b32_f16 %0, %1, %2" : "=v"(d) : "v"(lo), "v"(hi));
  return d;
}
// re^2 + im^2 accumulated in f32.
__device__ __forceinline__ float hdot2(float s, float acc) {
  float d;
  asm("v_dot2_f32_f16 %0, %1, %1, %2" : "=v"(d) : "v"(s), "v"(acc));
  return d;
}

// Gate on state bit P; u00p,u01p = packed f16 first row. sgnh/sgnl: per-lane
// sign masks (bit31 / bit15) for this gate's lane bit (0 for P<4).
// SW: pending xor-32 lane swap on odd regs consumed here (P==9 only).
template<int P, bool SW>
__device__ __forceinline__ void apply_u(float (&s)[16], float u00p, float u01p,
                                        int sgnh, int sgnl) {
  if constexpr (P < 4) {
    constexpr int bit = 1 << P;
#pragma unroll
    for (int r = 0; r < 16; ++r) {
      if ((r & bit) == 0) {
        int r1 = r | bit;
        float a0 = s[r], a1 = s[r1];
        s[r]  = hcfma(u01p, a1, hcmul(u00p, a0));     // u00*a0 + u01*a1
        s[r1] = hcfmamc(u01p, a0, hcmulc(u00p, a1));  // conj(u00)*a1 - conj(u01)*a0
      }
    }
  } else {
    constexpr int mask = 1 << (P - 4);
    // hi lane: self = conj(u00) (flip im=hi sign), partner = -conj(u01)
    // (flip re=lo sign); lo lane: u00, u01.
    float cA = fxor(u00p, sgnh);
    float cB = fxor(u01p, sgnl);
#pragma unroll
    for (int r = 0; r < 16; ++r) {
      float p = lxor<mask>(s[r]);
      if constexpr (SW) {
        if (r & 1) { s[r] = hcfma(cA, p, hcmul(cB, s[r])); continue; }
      }
      s[r] = hcfma(cB, p, hcmul(cA, s[r]));
    }
  }
}

// CNOT chain: (9,8)(8,7)(7,6)(6,5)(5,4) composed bpermute | (4,3) cndmask |
// (3,2)(2,1)(1,0) reg swaps | (0,9) DEFERRED.
__device__ __forceinline__ void cnot_block(float (&s)[16], int lane, int srcl4) {
#pragma unroll
  for (int r = 0; r < 16; ++r)
    s[r] = bperm_f(srcl4, s[r]);
  bool ctrl = (lane & 1) != 0;
#pragma unroll
  for (int r = 0; r < 8; ++r) {
    int r1 = r | 8;
    float t0 = s[r], t1 = s[r1];
    s[r]  = ctrl ? t1 : t0;
    s[r1] = ctrl ? t0 : t1;
  }
#pragma unroll
  for (int r = 8; r < 12; ++r) { float t = s[r]; s[r] = s[r | 4]; s[r | 4] = t; }
  {
    const int rs[4] = {4, 5, 12, 13};
#pragma unroll
    for (int k = 0; k < 4; ++k) {
      int r = rs[k];
      float t = s[r]; s[r] = s[r | 2]; s[r | 2] = t;
    }
  }
#pragma unroll
  for (int r = 2; r < 16; r += 4) { float t = s[r]; s[r] = s[r | 1]; s[r | 1] = t; }
}

// Layer 0 on |0>: product state. Wire w (0..5) -> lane bit (5-w);
// wires 6..9 -> reg bits 3..0. amp = prod of column-0 entries
// (col0 = {u00, -conj(u01)}), built f32 then packed f16.
__device__ __forceinline__ void init_product(float (&s)[16], const float4* wmat,
                                             float cx, float sx, int lane) {
  float u0p, u1p;
#define C0(i) { float4 wa = wmat[(i)]; \
    v2 wa0 = {wa.x, wa.y}, wa1 = {wa.z, wa.w}; \
    float ca = readlane_f(cx, (i)), sa = readlane_f(sx, (i)); \
    v2 u0 = ca * wa0 + sa * wa1; \
    v2 t01 = ca * wa1 - sa * wa0; \
    u0p = pack16(u0.x, u0.y); \
    u1p = pack16(-t01.x, t01.y); }
  float f;
  C0(0); f = (lane & 32) ? u1p : u0p;
  C0(1); f = hcmul((lane & 16) ? u1p : u0p, f);
  C0(2); f = hcmul((lane & 8) ? u1p : u0p, f);
  C0(3); f = hcmul((lane & 4) ? u1p : u0p, f);
  C0(4); f = hcmul((lane & 2) ? u1p : u0p, f);
  C0(5); f = hcmul((lane & 1) ? u1p : u0p, f);
  float q6_0, q6_1, q7_0, q7_1, q8_0, q8_1, q9_0, q9_1;
  C0(6); q6_0 = u0p; q6_1 = u1p;
  C0(7); q7_0 = u0p; q7_1 = u1p;
  C0(8); q8_0 = u0p; q8_1 = u1p;
  C0(9); q9_0 = u0p; q9_1 = u1p;
#undef C0
  float qa0 = hcmul(q8_0, q9_0), qa1 = hcmul(q8_0, q9_1);
  float qa2 = hcmul(q8_1, q9_0), qa3 = hcmul(q8_1, q9_1);
  float qb0 = hcmul(q6_0, q7_0), qb1 = hcmul(q6_0, q7_1);
  float qb2 = hcmul(q6_1, q7_0), qb3 = hcmul(q6_1, q7_1);
  float fa0 = hcmul(qa0, f), fa1 = hcmul(qa1, f), fa2 = hcmul(qa2, f), fa3 = hcmul(qa3, f);
  s[0]  = hcmul(qb0, fa0); s[1]  = hcmul(qb0, fa1); s[2]  = hcmul(qb0, fa2); s[3]  = hcmul(qb0, fa3);
  s[4]  = hcmul(qb1, fa0); s[5]  = hcmul(qb1, fa1); s[6]  = hcmul(qb1, fa2); s[7]  = hcmul(qb1, fa3);
  s[8]  = hcmul(qb2, fa0); s[9]  = hcmul(qb2, fa1); s[10] = hcmul(qb2, fa2); s[11] = hcmul(qb2, fa3);
  s[12] = hcmul(qb3, fa0); s[13] = hcmul(qb3, fa1); s[14] = hcmul(qb3, fa2); s[15] = hcmul(qb3, fa3);
}

template<int L, bool PEND>
__device__ __forceinline__ void layer_gates(float (&s)[16], const float4* wmat,
                                            float cxv, float sxv,
                                            const int (&sgnh)[6], const int (&sgnl)[6]) {
#define FUSED(i, SW) { \
    float4 wa = wmat[L * NQ + (i)]; \
    float ca = readlane_f(cxv, (i)); \
    float sa = readlane_f(sxv, (i)); \
    v2 wa0 = {wa.x, wa.y}, wa1 = {wa.z, wa.w}; \
    v2 u00 = ca * wa0 + sa * wa1, u01 = ca * wa1 - sa * wa0; \
    float u00p = pack16(u00.x, u00.y), u01p = pack16(u01.x, u01.y); \
    apply_u<9 - (i), SW>(s, u00p, u01p, \
        ((i) < 6) ? sgnh[5 - (i)] : 0, ((i) < 6) ? sgnl[5 - (i)] : 0); }
  FUSED(0, PEND)            // wire0 = bit9 = lane xor 32; consumes pending swap
  FUSED(1, false) FUSED(2, false) FUSED(3, false) FUSED(4, false)
  FUSED(5, false) FUSED(6, false) FUSED(7, false) FUSED(8, false) FUSED(9, false)
#undef FUSED
}

__global__ __launch_bounds__(256, 7) void qsim(const float* __restrict__ x,
                                               const float* __restrict__ w,
                                               float* __restrict__ out, int batch) {
  // Batch-shared fused weight matrices W = RZ(w2)*RY(w1)*RZ(w0); SU(2), so
  // only the first ROW (w00, w01) is stored (f32 for accuracy).
  __shared__ float4 wmat[NL * NQ];
  int tid = threadIdx.x;
  if (tid < NL * NQ) {
    const float* wp = &w[tid * 3];
    float t0 = 0.5f * wp[0], t1 = 0.5f * wp[1], t2 = 0.5f * wp[2];
    float c1, s1; sincosf(t1, &s1, &c1);
    float cA, sA; sincosf(t0 + t2, &sA, &cA);
    float cB, sB; sincosf(t0 - t2, &sB, &cB);
    wmat[tid] = make_float4(c1 * cA, -c1 * sA, -s1 * cB, -s1 * sB);
  }
  __syncthreads();

  int lane = tid & 63;
  int b = blockIdx.x * 4 + (tid >> 6);
  if (b >= batch) return;

  float cxv = 1.0f, sxv = 0.0f;
  if (lane < NQ) {
    float th = tanhf(x[b * NQ + lane]) * PI_F;
    sincosf(0.5f * th, &sxv, &cxv);
  }

  // Composed lane-permutation for the 5 lane-lane CNOTs.
  int srcl4;
  {
    int t = lane;
    t ^= (t >> 1) & 1;
    t ^= ((t >> 2) & 1) << 1;
    t ^= ((t >> 3) & 1) << 2;
    t ^= ((t >> 4) & 1) << 3;
    t ^= ((t >> 5) & 1) << 4;
    srcl4 = t << 2;
  }

  // Per-lane sign masks for lane bit k: hi-half (im) bit31, lo-half (re) bit15.
  int sgnh[6], sgnl[6];
#pragma unroll
  for (int k = 0; k < 6; ++k) {
    int bit = (lane >> k) & 1;
    sgnh[k] = bit << 31;
    sgnl[k] = bit << 15;
  }

  float s[16];
  // Layer 0 single-qubit part: direct product state (|0> start), then CNOTs.
  init_product(s, wmat, cxv, sxv, lane);
  cnot_block(s, lane, srcl4);

  layer_gates<1, true>(s, wmat, cxv, sxv, sgnh, sgnl);
  cnot_block(s, lane, srcl4);
  layer_gates<2, true>(s, wmat, cxv, sxv, sgnh, sgnl);
  cnot_block(s, lane, srcl4);
  layer_gates<3, true>(s, wmat, cxv, sxv, sgnh, sgnl);
  // Layer 3's FULL CNOT chain absorbed into measurement sign masks (Fi).

  // prob in exact f32 via v_dot2_f32_f16.
  float prob[16];
#pragma unroll
  for (int r = 0; r < 16; ++r)
    prob[r] = hdot2(s[r], 0.0f);

  float S0 = 0.0f, S8 = 0.0f, SC = 0.0f, SE = 0.0f, SF = 0.0f;
#pragma unroll
  for (int r = 0; r < 16; ++r) {
    float pr = prob[r];
    S0 += pr;
    S8 += (__builtin_popcount(r & 0x8) & 1) ? -pr : pr;
    SC += (__builtin_popcount(r & 0xC) & 1) ? -pr : pr;
    SE += (__builtin_popcount(r & 0xE) & 1) ? -pr : pr;
    SF += (__builtin_popcount(r & 0xF) & 1) ? -pr : pr;
  }

  // Lane suffix parities (Fi rows).
  int l0 = lane & 1, l1 = (lane >> 1) & 1, l2 = (lane >> 2) & 1;
  int l3 = (lane >> 3) & 1, l4 = (lane >> 4) & 1, l5 = (lane >> 5) & 1;
  int p30 = l4 ^ l5;
  int p38 = p30 ^ l3;
  int p3C = p38 ^ l2;
  int p3E = p3C ^ l1;
  int p3F = p3E ^ l0;
  int p1F = p3F ^ l5;

  float part[10];
  part[0] = p3F ? -SF : SF;
  part[1] = p3F ? -SE : SE;
  part[2] = p3F ? -SC : SC;
  part[3] = p3F ? -S8 : S8;
  part[4] = p3F ? -S0 : S0;
  part[5] = p3E ? -S0 : S0;
  part[6] = p3C ? -S0 : S0;
  part[7] = p38 ? -S0 : S0;
  part[8] = p30 ? -S0 : S0;
  part[9] = p1F ? -SF : SF;

#pragma unroll
  for (int p = 0; p < 10; ++p) {
    float a = part[p];
    a += lxor<1>(a);
    a += lxor<2>(a);
    a += lxor<4>(a);
    a += lxor<8>(a);
    a = plsum16(a);
    a = plsum32(a);
    part[p] = a;
  }

  if (lane == 0) {
#pragma unroll
    for (int q = 0; q < NQ; ++q)
      out[b * NQ + q] = part[9 - q];
  }
}

}  // namespace

extern "C" void kernel_launch(void* const* d_in, const int* in_sizes, int n_in,
                              void* d_out, int out_size, void* d_ws, size_t ws_size,
                              hipStream_t stream) {
  const float* x = (const float*)d_in[0];
  const float* w = (const float*)d_in[1];
  float* out = (float*)d_out;
  int batch = in_sizes[0] / NQ;
  int blocks = (batch + 3) / 4;  // 4 waves/block, 1 batch element per wave
  qsim<<<blocks, 256, 0, stream>>>(x, w, out, batch);
}

// Round 21
// 137.096 us; speedup vs baseline: 1.1982x; 1.0003x over previous
//
#include <hip/hip_runtime.h>
#include <math.h>

namespace {

constexpr int NQ = 10;
constexpr int NL = 4;
constexpr float PI_F = 3.14159265358979323846f;

// One batch element per wave. Each complex amp packed as f16 {re=lo, im=hi}
// in ONE 32-bit VGPR (carrier type: float). Complex math via v_pk_fma_f16
// with the SAME VOP3P op_sel/neg modifiers as the verified f32 version
// (R14/R15/R16) — f16 pk ops run at 2x the f32 pk rate AND halve every
// lane-exchange (one b32 per amp). SU(2): only u00,u01 built; second row
// via conjugated variants; lane-gate coefficient selects are sign-bit XORs
// (hi-half bit31 for im, lo-half bit15 for re). Conversions f32->f16 use
// RNE (v_cvt_f16_f32 + v_pack_b32_f16). prob = v_dot2_f32_f16(s,s,0).
// Structure: DPP masks 1,2,8; ds_swizzle 4,16,32; composed 5-CNOT bpermute;
// C(9->0) deferred; final CNOT chain absorbed into measurement sign masks.
// R21: launch_bounds (256,7)->(256,8). R20's compiled pressure is 32 VGPR,
// far under the 64-cap of 8 waves/EU -> no spill possible, +1 resident
// wave/SIMD of latency hiding. (R14's spill under (256,8) was the f32 body
// whose natural pressure exceeded 64; the f16 body fits in 32.)

typedef float v2 __attribute__((ext_vector_type(2)));

// ---- GF(2) verification of the absorbed CNOT map (compile-time only) ----
struct M10 { unsigned r[10]; };
constexpr M10 I10{{1u,2u,4u,8u,16u,32u,64u,128u,256u,512u}};
constexpr M10 Fm{{0x003u,0x006u,0x00Cu,0x018u,0x030u,0x060u,0x0C0u,0x180u,0x301u,0x201u}};
constexpr M10 Fi{{0x3FFu,0x3FEu,0x3FCu,0x3F8u,0x3F0u,0x3E0u,0x3C0u,0x380u,0x300u,0x1FFu}};
constexpr M10 mmul(const M10& A, const M10& B) {
  M10 C{};
  for (int p = 0; p < 10; ++p) {
    unsigned v = 0;
    for (int q = 0; q < 10; ++q)
      if ((A.r[p] >> q) & 1u) v ^= B.r[q];
    C.r[p] = v;
  }
  return C;
}
constexpr bool meq(const M10& A, const M10& B) {
  for (int p = 0; p < 10; ++p) if (A.r[p] != B.r[p]) return false;
  return true;
}
static_assert(meq(mmul(Fm, Fi), I10), "Fi is not F^-1");

__device__ __forceinline__ float readlane_f(float v, int lane_const) {
  return __int_as_float(__builtin_amdgcn_readlane(__float_as_int(v), lane_const));
}
__device__ __forceinline__ float bperm_f(int addr4, float v) {
  return __int_as_float(__builtin_amdgcn_ds_bpermute(addr4, __float_as_int(v)));
}
__device__ __forceinline__ float fxor(float v, int m) {
  return __int_as_float(__float_as_int(v) ^ m);
}

// own + partner — direction-agnostic permlane sum (R11-verified); used in
// the measurement butterfly only.
__device__ __forceinline__ float plsum32(float v) {
  float a = v, b = v;
  asm("v_permlane32_swap_b32 %0, %1" : "+v"(a), "+v"(b));
  return a + b;
}
__device__ __forceinline__ float plsum16(float v) {
  float a = v, b = v;
  asm("v_permlane16_swap_b32 %0, %1" : "+v"(a), "+v"(b));
  return a + b;
}

// xor-lane exchange for masks 1,2,8 (DPP) and 4,16,32 (ds_swizzle).
template<int MASK>
__device__ __forceinline__ float lxor(float v) {
  if constexpr (MASK == 1 || MASK == 2 || MASK == 8) {
    constexpr int ctrl = (MASK == 1) ? 0xB1 : (MASK == 2) ? 0x4E : 0x128;
    int i = __float_as_int(v);
    return __int_as_float(__builtin_amdgcn_update_dpp(i, i, ctrl, 0xF, 0xF, true));
  } else {
    return __shfl_xor(v, MASK, 64);
  }
}

// ---- packed complex f16 arithmetic ({re,im} in ONE VGPR) ----
// d = u (*) a
__device__ __forceinline__ float hcmul(float u, float a) {
  float d;
  asm("v_pk_mul_f16 %0, %1, %2 op_sel:[0,0] op_sel_hi:[0,1]\n\t"
      "v_pk_fma_f16 %0, %1, %2, %0 op_sel:[1,1,0] op_sel_hi:[1,0,1] neg_lo:[1,0,0]"
      : "=&v"(d) : "v"(u), "v"(a));
  return d;
}
// d = acc + u (*) a
__device__ __forceinline__ float hcfma(float u, float a, float acc) {
  float d;
  asm("v_pk_fma_f16 %0, %1, %2, %3 op_sel:[0,0,0] op_sel_hi:[0,1,1]\n\t"
      "v_pk_fma_f16 %0, %1, %2, %0 op_sel:[1,1,0] op_sel_hi:[1,0,1] neg_lo:[1,0,0]"
      : "=&v"(d) : "v"(u), "v"(a), "v"(acc));
  return d;
}
// d = conj(u) (*) a
__device__ __forceinline__ float hcmulc(float u, float a) {
  float d;
  asm("v_pk_mul_f16 %0, %1, %2 op_sel:[0,0] op_sel_hi:[0,1]\n\t"
      "v_pk_fma_f16 %0, %1, %2, %0 op_sel:[1,1,0] op_sel_hi:[1,0,1] neg_hi:[1,0,0]"
      : "=&v"(d) : "v"(u), "v"(a));
  return d;
}
// d = acc - conj(u) (*) a
__device__ __forceinline__ float hcfmamc(float u, float a, float acc) {
  float d;
  asm("v_pk_fma_f16 %0, %1, %2, %3 op_sel:[0,0,0] op_sel_hi:[0,1,1] neg_lo:[1,0,0] neg_hi:[1,0,0]\n\t"
      "v_pk_fma_f16 %0, %1, %2, %0 op_sel:[1,1,0] op_sel_hi:[1,0,1] neg_lo:[1,0,0]"
      : "=&v"(d) : "v"(u), "v"(a), "v"(acc));
  return d;
}
// RNE pack: two f32 -> packed f16 pair.
__device__ __forceinline__ float pack16(float x, float y) {
  float lo, hi, d;
  asm("v_cvt_f16_f32 %0, %1" : "=v"(lo) : "v"(x));
  asm("v_cvt_f16_f32 %0, %1" : "=v"(hi) : "v"(y));
  asm("v_pack_b32_f16 %0, %1, %2" : "=v"(d) : "v"(lo), "v"(hi));
  return d;
}
// re^2 + im^2 accumulated in f32.
__device__ __forceinline__ float hdot2(float s, float acc) {
  float d;
  asm("v_dot2_f32_f16 %0, %1, %1, %2" : "=v"(d) : "v"(s), "v"(acc));
  return d;
}

// Gate on state bit P; u00p,u01p = packed f16 first row. sgnh/sgnl: per-lane
// sign masks (bit31 / bit15) for this gate's lane bit (0 for P<4).
// SW: pending xor-32 lane swap on odd regs consumed here (P==9 only).
template<int P, bool SW>
__device__ __forceinline__ void apply_u(float (&s)[16], float u00p, float u01p,
                                        int sgnh, int sgnl) {
  if constexpr (P < 4) {
    constexpr int bit = 1 << P;
#pragma unroll
    for (int r = 0; r < 16; ++r) {
      if ((r & bit) == 0) {
        int r1 = r | bit;
        float a0 = s[r], a1 = s[r1];
        s[r]  = hcfma(u01p, a1, hcmul(u00p, a0));     // u00*a0 + u01*a1
        s[r1] = hcfmamc(u01p, a0, hcmulc(u00p, a1));  // conj(u00)*a1 - conj(u01)*a0
      }
    }
  } else {
    constexpr int mask = 1 << (P - 4);
    // hi lane: self = conj(u00) (flip im=hi sign), partner = -conj(u01)
    // (flip re=lo sign); lo lane: u00, u01.
    float cA = fxor(u00p, sgnh);
    float cB = fxor(u01p, sgnl);
#pragma unroll
    for (int r = 0; r < 16; ++r) {
      float p = lxor<mask>(s[r]);
      if constexpr (SW) {
        if (r & 1) { s[r] = hcfma(cA, p, hcmul(cB, s[r])); continue; }
      }
      s[r] = hcfma(cB, p, hcmul(cA, s[r]));
    }
  }
}

// CNOT chain: (9,8)(8,7)(7,6)(6,5)(5,4) composed bpermute | (4,3) cndmask |
// (3,2)(2,1)(1,0) reg swaps | (0,9) DEFERRED.
__device__ __forceinline__ void cnot_block(float (&s)[16], int lane, int srcl4) {
#pragma unroll
  for (int r = 0; r < 16; ++r)
    s[r] = bperm_f(srcl4, s[r]);
  bool ctrl = (lane & 1) != 0;
#pragma unroll
  for (int r = 0; r < 8; ++r) {
    int r1 = r | 8;
    float t0 = s[r], t1 = s[r1];
    s[r]  = ctrl ? t1 : t0;
    s[r1] = ctrl ? t0 : t1;
  }
#pragma unroll
  for (int r = 8; r < 12; ++r) { float t = s[r]; s[r] = s[r | 4]; s[r | 4] = t; }
  {
    const int rs[4] = {4, 5, 12, 13};
#pragma unroll
    for (int k = 0; k < 4; ++k) {
      int r = rs[k];
      float t = s[r]; s[r] = s[r | 2]; s[r | 2] = t;
    }
  }
#pragma unroll
  for (int r = 2; r < 16; r += 4) { float t = s[r]; s[r] = s[r | 1]; s[r | 1] = t; }
}

// Layer 0 on |0>: product state. Wire w (0..5) -> lane bit (5-w);
// wires 6..9 -> reg bits 3..0. amp = prod of column-0 entries
// (col0 = {u00, -conj(u01)}), built f32 then packed f16.
__device__ __forceinline__ void init_product(float (&s)[16], const float4* wmat,
                                             float cx, float sx, int lane) {
  float u0p, u1p;
#define C0(i) { float4 wa = wmat[(i)]; \
    v2 wa0 = {wa.x, wa.y}, wa1 = {wa.z, wa.w}; \
    float ca = readlane_f(cx, (i)), sa = readlane_f(sx, (i)); \
    v2 u0 = ca * wa0 + sa * wa1; \
    v2 t01 = ca * wa1 - sa * wa0; \
    u0p = pack16(u0.x, u0.y); \
    u1p = pack16(-t01.x, t01.y); }
  float f;
  C0(0); f = (lane & 32) ? u1p : u0p;
  C0(1); f = hcmul((lane & 16) ? u1p : u0p, f);
  C0(2); f = hcmul((lane & 8) ? u1p : u0p, f);
  C0(3); f = hcmul((lane & 4) ? u1p : u0p, f);
  C0(4); f = hcmul((lane & 2) ? u1p : u0p, f);
  C0(5); f = hcmul((lane & 1) ? u1p : u0p, f);
  float q6_0, q6_1, q7_0, q7_1, q8_0, q8_1, q9_0, q9_1;
  C0(6); q6_0 = u0p; q6_1 = u1p;
  C0(7); q7_0 = u0p; q7_1 = u1p;
  C0(8); q8_0 = u0p; q8_1 = u1p;
  C0(9); q9_0 = u0p; q9_1 = u1p;
#undef C0
  float qa0 = hcmul(q8_0, q9_0), qa1 = hcmul(q8_0, q9_1);
  float qa2 = hcmul(q8_1, q9_0), qa3 = hcmul(q8_1, q9_1);
  float qb0 = hcmul(q6_0, q7_0), qb1 = hcmul(q6_0, q7_1);
  float qb2 = hcmul(q6_1, q7_0), qb3 = hcmul(q6_1, q7_1);
  float fa0 = hcmul(qa0, f), fa1 = hcmul(qa1, f), fa2 = hcmul(qa2, f), fa3 = hcmul(qa3, f);
  s[0]  = hcmul(qb0, fa0); s[1]  = hcmul(qb0, fa1); s[2]  = hcmul(qb0, fa2); s[3]  = hcmul(qb0, fa3);
  s[4]  = hcmul(qb1, fa0); s[5]  = hcmul(qb1, fa1); s[6]  = hcmul(qb1, fa2); s[7]  = hcmul(qb1, fa3);
  s[8]  = hcmul(qb2, fa0); s[9]  = hcmul(qb2, fa1); s[10] = hcmul(qb2, fa2); s[11] = hcmul(qb2, fa3);
  s[12] = hcmul(qb3, fa0); s[13] = hcmul(qb3, fa1); s[14] = hcmul(qb3, fa2); s[15] = hcmul(qb3, fa3);
}

template<int L, bool PEND>
__device__ __forceinline__ void layer_gates(float (&s)[16], const float4* wmat,
                                            float cxv, float sxv,
                                            const int (&sgnh)[6], const int (&sgnl)[6]) {
#define FUSED(i, SW) { \
    float4 wa = wmat[L * NQ + (i)]; \
    float ca = readlane_f(cxv, (i)); \
    float sa = readlane_f(sxv, (i)); \
    v2 wa0 = {wa.x, wa.y}, wa1 = {wa.z, wa.w}; \
    v2 u00 = ca * wa0 + sa * wa1, u01 = ca * wa1 - sa * wa0; \
    float u00p = pack16(u00.x, u00.y), u01p = pack16(u01.x, u01.y); \
    apply_u<9 - (i), SW>(s, u00p, u01p, \
        ((i) < 6) ? sgnh[5 - (i)] : 0, ((i) < 6) ? sgnl[5 - (i)] : 0); }
  FUSED(0, PEND)            // wire0 = bit9 = lane xor 32; consumes pending swap
  FUSED(1, false) FUSED(2, false) FUSED(3, false) FUSED(4, false)
  FUSED(5, false) FUSED(6, false) FUSED(7, false) FUSED(8, false) FUSED(9, false)
#undef FUSED
}

__global__ __launch_bounds__(256, 8) void qsim(const float* __restrict__ x,
                                               const float* __restrict__ w,
                                               float* __restrict__ out, int batch) {
  // Batch-shared fused weight matrices W = RZ(w2)*RY(w1)*RZ(w0); SU(2), so
  // only the first ROW (w00, w01) is stored (f32 for accuracy).
  __shared__ float4 wmat[NL * NQ];
  int tid = threadIdx.x;
  if (tid < NL * NQ) {
    const float* wp = &w[tid * 3];
    float t0 = 0.5f * wp[0], t1 = 0.5f * wp[1], t2 = 0.5f * wp[2];
    float c1, s1; sincosf(t1, &s1, &c1);
    float cA, sA; sincosf(t0 + t2, &sA, &cA);
    float cB, sB; sincosf(t0 - t2, &sB, &cB);
    wmat[tid] = make_float4(c1 * cA, -c1 * sA, -s1 * cB, -s1 * sB);
  }
  __syncthreads();

  int lane = tid & 63;
  int b = blockIdx.x * 4 + (tid >> 6);
  if (b >= batch) return;

  float cxv = 1.0f, sxv = 0.0f;
  if (lane < NQ) {
    float th = tanhf(x[b * NQ + lane]) * PI_F;
    sincosf(0.5f * th, &sxv, &cxv);
  }

  // Composed lane-permutation for the 5 lane-lane CNOTs.
  int srcl4;
  {
    int t = lane;
    t ^= (t >> 1) & 1;
    t ^= ((t >> 2) & 1) << 1;
    t ^= ((t >> 3) & 1) << 2;
    t ^= ((t >> 4) & 1) << 3;
    t ^= ((t >> 5) & 1) << 4;
    srcl4 = t << 2;
  }

  // Per-lane sign masks for lane bit k: hi-half (im) bit31, lo-half (re) bit15.
  int sgnh[6], sgnl[6];
#pragma unroll
  for (int k = 0; k < 6; ++k) {
    int bit = (lane >> k) & 1;
    sgnh[k] = bit << 31;
    sgnl[k] = bit << 15;
  }

  float s[16];
  // Layer 0 single-qubit part: direct product state (|0> start), then CNOTs.
  init_product(s, wmat, cxv, sxv, lane);
  cnot_block(s, lane, srcl4);

  layer_gates<1, true>(s, wmat, cxv, sxv, sgnh, sgnl);
  cnot_block(s, lane, srcl4);
  layer_gates<2, true>(s, wmat, cxv, sxv, sgnh, sgnl);
  cnot_block(s, lane, srcl4);
  layer_gates<3, true>(s, wmat, cxv, sxv, sgnh, sgnl);
  // Layer 3's FULL CNOT chain absorbed into measurement sign masks (Fi).

  // prob in exact f32 via v_dot2_f32_f16.
  float prob[16];
#pragma unroll
  for (int r = 0; r < 16; ++r)
    prob[r] = hdot2(s[r], 0.0f);

  float S0 = 0.0f, S8 = 0.0f, SC = 0.0f, SE = 0.0f, SF = 0.0f;
#pragma unroll
  for (int r = 0; r < 16; ++r) {
    float pr = prob[r];
    S0 += pr;
    S8 += (__builtin_popcount(r & 0x8) & 1) ? -pr : pr;
    SC += (__builtin_popcount(r & 0xC) & 1) ? -pr : pr;
    SE += (__builtin_popcount(r & 0xE) & 1) ? -pr : pr;
    SF += (__builtin_popcount(r & 0xF) & 1) ? -pr : pr;
  }

  // Lane suffix parities (Fi rows).
  int l0 = lane & 1, l1 = (lane >> 1) & 1, l2 = (lane >> 2) & 1;
  int l3 = (lane >> 3) & 1, l4 = (lane >> 4) & 1, l5 = (lane >> 5) & 1;
  int p30 = l4 ^ l5;
  int p38 = p30 ^ l3;
  int p3C = p38 ^ l2;
  int p3E = p3C ^ l1;
  int p3F = p3E ^ l0;
  int p1F = p3F ^ l5;

  float part[10];
  part[0] = p3F ? -SF : SF;
  part[1] = p3F ? -SE : SE;
  part[2] = p3F ? -SC : SC;
  part[3] = p3F ? -S8 : S8;
  part[4] = p3F ? -S0 : S0;
  part[5] = p3E ? -S0 : S0;
  part[6] = p3C ? -S0 : S0;
  part[7] = p38 ? -S0 : S0;
  part[8] = p30 ? -S0 : S0;
  part[9] = p1F ? -SF : SF;

#pragma unroll
  for (int p = 0; p < 10; ++p) {
    float a = part[p];
    a += lxor<1>(a);
    a += lxor<2>(a);
    a += lxor<4>(a);
    a += lxor<8>(a);
    a = plsum16(a);
    a = plsum32(a);
    part[p] = a;
  }

  if (lane == 0) {
#pragma unroll
    for (int q = 0; q < NQ; ++q)
      out[b * NQ + q] = part[9 - q];
  }
}

}  // namespace

extern "C" void kernel_launch(void* const* d_in, const int* in_sizes, int n_in,
                              void* d_out, int out_size, void* d_ws, size_t ws_size,
                              hipStream_t stream) {
  const float* x = (const float*)d_in[0];
  const float* w = (const float*)d_in[1];
  float* out = (float*)d_out;
  int batch = in_sizes[0] / NQ;
  int blocks = (batch + 3) / 4;  // 4 waves/block, 1 batch element per wave
  qsim<<<blocks, 256, 0, stream>>>(x, w, out, batch);
}